// Round 18
// baseline (236.158 us; speedup 1.0000x reference)
//
#include <hip/hip_runtime.h>
#include <hip/hip_bf16.h>
#include <math.h>

#define DDIM 1024
#define NH 16
#define HDIM 64
#define SCALE 0.125f
#define DLAM -0.1f
#define LNEPS 1e-5f
#define NS 16      // n-splits (blocks per batch)
#define CHW 16     // chunk height (rows per chunk)
#define BROW 256   // rows per block = N/NS
#define CBSTR 1032 // padded LDS row stride (bf16 elems)

typedef short bf16x8 __attribute__((ext_vector_type(8)));
typedef float f32x4 __attribute__((ext_vector_type(4)));

__device__ inline unsigned short f2bf(float x) {
    return __builtin_bit_cast(unsigned short, __float2bfloat16(x));
}
__device__ inline float bf2f(unsigned short u) {
    return __builtin_bit_cast(float, (unsigned)u << 16);
}

// LDS-only barrier: waits DS ops (lgkmcnt) but leaves global loads in flight.
__device__ inline void wg_barrier_lds() {
    asm volatile("s_waitcnt lgkmcnt(0)" ::: "memory");
    __builtin_amdgcn_s_barrier();
    __builtin_amdgcn_sched_barrier(0);
}

// K1: q[b,c] = query[b,:] @ Wq[:,c] + bq[c]; grid (B,8)
__global__ __launch_bounds__(512) void k_q(const float* __restrict__ query,
                                           const float* __restrict__ Wq,
                                           const float* __restrict__ bq,
                                           float* __restrict__ qout) {
    int b = blockIdx.x, c0 = blockIdx.y * 128;
    __shared__ float qs[DDIM];
    __shared__ float ps[512];
    int t = threadIdx.x;
    for (int i = t; i < DDIM; i += 512) qs[i] = query[b * DDIM + i];
    __syncthreads();
    int cl = t & 127;
    int col = c0 + cl;
    int d0 = (t >> 7) * 256;
    float acc = 0.f;
#pragma unroll 8
    for (int d = d0; d < d0 + 256; ++d)
        acc = fmaf(qs[d], Wq[(size_t)d * DDIM + col], acc);
    ps[t] = acc;
    __syncthreads();
    if (t < 128)
        qout[b * DDIM + col] = ps[t] + ps[t + 128] + ps[t + 256] + ps[t + 384] + bq[col];
}

// K2: qpb[(bg*8+bb),h,d] = bf16( SCALE * sum_j Wk[d, h*64+j] * q[bb, h*64+j] )
// sb folded into dt==0 blocks.
__global__ __launch_bounds__(256) void k_qp(const float* __restrict__ qin,
                                            const float* __restrict__ Wk,
                                            const float* __restrict__ bk,
                                            unsigned short* __restrict__ qpb,
                                            float* __restrict__ sb) {
    int dt = blockIdx.x, bg = blockIdx.y;
    __shared__ float qs[8][DDIM];  // 32 KB
    for (int i = threadIdx.x; i < 8 * DDIM; i += 256)
        qs[i >> 10][i & 1023] =
            qin[(size_t)(bg * 8 + (i >> 10)) * DDIM + (i & 1023)];
    __syncthreads();
    if (dt == 0 && threadIdx.x < 128) {
        int bb = threadIdx.x >> 4, h = threadIdx.x & 15;
        float a = 0.f;
#pragma unroll
        for (int j = 0; j < HDIM; ++j)
            a = fmaf(bk[h * HDIM + j], qs[bb][h * HDIM + j], a);
        sb[(bg * 8 + bb) * NH + h] = a * SCALE;
    }
    int h = threadIdx.x & 15, dl = threadIdx.x >> 4;
    int d = dt * 16 + dl;
    const float* wr = Wk + (size_t)d * DDIM + h * HDIM;
    float acc[8] = {0.f, 0.f, 0.f, 0.f, 0.f, 0.f, 0.f, 0.f};
#pragma unroll
    for (int j = 0; j < HDIM; ++j) {
        float wv = wr[j];
#pragma unroll
        for (int bb = 0; bb < 8; ++bb)
            acc[bb] = fmaf(wv, qs[bb][h * HDIM + j], acc[bb]);
    }
#pragma unroll
    for (int bb = 0; bb < 8; ++bb)
        qpb[((size_t)((bg * 8 + bb) * NH + h)) * DDIM + d] = f2bf(acc[bb] * SCALE);
}

// K3 (fused flash v3): 512 thr = 8 waves, k-slice 128/wave. cbuf is
// WAVE-PRIVATE (each wave stages+reads only cols [w*128,w*128+128)) ->
// single-buffered, no barrier needed for it (per-wave in-order DS FIFO).
// red double-buffered -> exactly ONE barrier per chunk.
__global__ __launch_bounds__(512, 4) void k_flash3(
    const float* __restrict__ ctx, const unsigned short* __restrict__ qpb,
    const float* __restrict__ sb, const float* __restrict__ dist,
    const int* __restrict__ mask, unsigned short* __restrict__ partAb,
    float* __restrict__ partM, float* __restrict__ partL, int N) {
    __shared__ unsigned short cbuf[CHW][CBSTR];  // 33024 B
    __shared__ float red[2][8][CHW][17];         // 17408 B
    __shared__ float dls[BROW];                  // 1024 B

    int b = blockIdx.x, ns = blockIdx.y;
    int t = threadIdx.x, lane = t & 63, w = t >> 6;
    int m = lane & 15, g = lane >> 4;
    int l5 = lane & 31, lh = lane >> 5;
    int nb0 = ns * BROW;
    const int NIT = BROW / CHW;  // 16

    if (t < BROW) {
        float dv = dist[(size_t)b * N + nb0 + t] * DLAM;
        dls[t] = mask[(size_t)b * N + nb0 + t] ? dv : -1e30f;
    }
    bf16x8 qf[4];
#pragma unroll
    for (int j = 0; j < 4; ++j)
        qf[j] = *reinterpret_cast<const bf16x8*>(
            qpb + ((size_t)(b * NH + m)) * DDIM + w * 128 + j * 32 + g * 8);
    float sbv = sb[b * NH + m];

    // acc[td][r] = out[h=g*4+r][d = w*128 + td*16 + m]
    f32x4 acc[8];
#pragma unroll
    for (int td = 0; td < 8; ++td) acc[td] = (f32x4){0.f, 0.f, 0.f, 0.f};
    float m_run = -1e30f, l_run = 0.f;

    const float4* cb4 = reinterpret_cast<const float4*>(ctx) +
                        ((size_t)b * N + nb0) * (DDIM / 4);
    float4 infl[8];

    // wave w stages rows {2i+lh}, float4-col (w*32 + l5) -> elem col w*128+l5*4
#define LOADC(c)                                                         \
    {                                                                    \
        _Pragma("unroll") for (int i = 0; i < 8; ++i)                    \
            infl[i] = cb4[(size_t)((c) * CHW + 2 * i + lh) * 256 + w * 32 + l5]; \
    }
#define WRITECB()                                                            \
    {                                                                        \
        _Pragma("unroll") for (int i = 0; i < 8; ++i) {                      \
            float4 v = infl[i];                                              \
            unsigned lo = (unsigned)f2bf(v.x) | ((unsigned)f2bf(v.y) << 16); \
            unsigned hi = (unsigned)f2bf(v.z) | ((unsigned)f2bf(v.w) << 16); \
            *reinterpret_cast<uint2*>(                                       \
                &cbuf[2 * i + lh][(w * 32 + l5) * 4]) = make_uint2(lo, hi);  \
        }                                                                    \
    }

    LOADC(0);
    WRITECB();
    LOADC(1);

    for (int c = 0; c < NIT; ++c) {
        int rb = c & 1;
        // ---- scores (wave k-slice 128; reads own cbuf slice, no barrier) ----
        f32x4 cS = {0.f, 0.f, 0.f, 0.f};
#pragma unroll
        for (int j = 0; j < 4; ++j) {
            bf16x8 a = *reinterpret_cast<const bf16x8*>(
                &cbuf[m][w * 128 + j * 32 + g * 8]);
            cS = __builtin_amdgcn_mfma_f32_16x16x32_bf16(a, qf[j], cS, 0, 0, 0);
        }
#pragma unroll
        for (int r = 0; r < 4; ++r) red[rb][w][g * 4 + r][m] = cS[r];
        wg_barrier_lds();  // THE one barrier: red[rb] ready
        float S[4];
#pragma unroll
        for (int r = 0; r < 4; ++r) {
            int n = g * 4 + r;
            float s = sbv + dls[c * CHW + n];
#pragma unroll
            for (int ww = 0; ww < 8; ++ww) s += red[rb][ww][n][m];
            S[r] = s;
        }
        float cm = fmaxf(fmaxf(S[0], S[1]), fmaxf(S[2], S[3]));
        cm = fmaxf(cm, __shfl_xor(cm, 16, 64));
        cm = fmaxf(cm, __shfl_xor(cm, 32, 64));
        float mnew = fmaxf(m_run, cm);
        float f = __expf(m_run - mnew);
        float p[4];
        float ls = 0.f;
#pragma unroll
        for (int r = 0; r < 4; ++r) {
            p[r] = __expf(S[r] - mnew);
            ls += p[r];
        }
        ls += __shfl_xor(ls, 16, 64);
        ls += __shfl_xor(ls, 32, 64);
        l_run = l_run * f + ls;
        m_run = mnew;
        // ---- A-frag from p; per-head rescale via shfl ----
        bf16x8 pa = (bf16x8){0, 0, 0, 0, 0, 0, 0, 0};
        pa[0] = (short)f2bf(p[0]);
        pa[1] = (short)f2bf(p[1]);
        pa[2] = (short)f2bf(p[2]);
        pa[3] = (short)f2bf(p[3]);
        float fr[4];
#pragma unroll
        for (int r = 0; r < 4; ++r) fr[r] = __shfl(f, (lane >> 4) * 4 + r, 64);
#pragma unroll
        for (int td = 0; td < 8; ++td) {
            acc[td][0] *= fr[0];
            acc[td][1] *= fr[1];
            acc[td][2] *= fr[2];
            acc[td][3] *= fr[3];
        }
        // ---- PV via MFMA (reads own cbuf slice) ----
#pragma unroll
        for (int td = 0; td < 8; ++td) {
            int dc = w * 128 + td * 16 + m;
            bf16x8 bb = (bf16x8){0, 0, 0, 0, 0, 0, 0, 0};
            bb[0] = (short)cbuf[g * 4 + 0][dc];
            bb[1] = (short)cbuf[g * 4 + 1][dc];
            bb[2] = (short)cbuf[g * 4 + 2][dc];
            bb[3] = (short)cbuf[g * 4 + 3][dc];
            acc[td] = __builtin_amdgcn_mfma_f32_16x16x32_bf16(pa, bb, acc[td], 0, 0, 0);
        }
        // ---- stage next chunk into (wave-private) cbuf; PV reads precede
        // these writes in the wave's in-order DS stream; pin compiler order.
        __builtin_amdgcn_sched_barrier(0);
        if (c + 1 < NIT) {
            WRITECB();
            if (c + 2 < NIT) LOADC(c + 2);
        }
        __builtin_amdgcn_sched_barrier(0);
    }

    // epilogue: bf16 partials; thread holds h=g*4+r, d=w*128+td*16+m
#pragma unroll
    for (int td = 0; td < 8; ++td) {
#pragma unroll
        for (int r = 0; r < 4; ++r) {
            int h = g * 4 + r;
            partAb[((size_t)((b * NS + ns) * NH + h)) * DDIM + w * 128 + td * 16 +
                   m] = f2bf(acc[td][r]);
        }
    }
    if (t < NH) {
        partM[(b * NS + ns) * NH + t] = m_run;
        partL[(b * NS + ns) * NH + t] = l_run;
    }
#undef LOADC
#undef WRITECB
}

// K4 (fused comb + vproj): grid (B, 8). Comb 2 heads from bf16 partA into LDS,
// then the k_vproj GEMV.
__global__ __launch_bounds__(256) void k_combv2(const unsigned short* __restrict__ partAb,
                                                const float* __restrict__ partM,
                                                const float* __restrict__ partL,
                                                const float* __restrict__ Wv,
                                                const float* __restrict__ bv,
                                                float* __restrict__ oattn) {
    int b = blockIdx.x, c0 = blockIdx.y * 128;
    int h0 = c0 >> 6;
    __shared__ float cs[2][DDIM];
    __shared__ float wn_s[2][NS];
    __shared__ float ps[256];
    int t = threadIdx.x;
    if (t < 2) {
        int h = h0 + t;
        float M = -1e30f;
#pragma unroll
        for (int ns = 0; ns < NS; ++ns)
            M = fmaxf(M, partM[(b * NS + ns) * NH + h]);
        float den = 0.f;
#pragma unroll
        for (int ns = 0; ns < NS; ++ns)
            den = fmaf(__expf(partM[(b * NS + ns) * NH + h] - M),
                       partL[(b * NS + ns) * NH + h], den);
        float inv = 1.f / den;
#pragma unroll
        for (int ns = 0; ns < NS; ++ns)
            wn_s[t][ns] = __expf(partM[(b * NS + ns) * NH + h] - M) * inv;
    }
    __syncthreads();
    for (int i = t; i < 2 * DDIM; i += 256) {
        int hh = i >> 10, d = i & 1023;
        float s = 0.f;
#pragma unroll
        for (int ns = 0; ns < NS; ++ns)
            s = fmaf(wn_s[hh][ns],
                     bf2f(partAb[((size_t)((b * NS + ns) * NH + h0 + hh)) * DDIM + d]),
                     s);
        cs[hh][d] = s;
    }
    __syncthreads();
    int cl = t & 127;
    int col = c0 + cl;
    int hl = cl >> 6;
    int d0 = (t >> 7) * 512;
    float acc = 0.f;
#pragma unroll 8
    for (int d = d0; d < d0 + 512; ++d)
        acc = fmaf(cs[hl][d], Wv[(size_t)d * DDIM + col], acc);
    ps[t] = acc;
    __syncthreads();
    if (t < 128) oattn[b * DDIM + col] = ps[t] + ps[t + 128] + bv[col];
}

// K5: x[b,c] = query[b,c] + oattn[b,:] . Wo[:,c] + bo[c]; grid (B, 8)
__global__ __launch_bounds__(256) void k_oproj(const float* __restrict__ query,
                                               const float* __restrict__ oattn,
                                               const float* __restrict__ Wo,
                                               const float* __restrict__ bo,
                                               float* __restrict__ x) {
    int b = blockIdx.x, c0 = blockIdx.y * 128;
    __shared__ float os[DDIM];
    __shared__ float ps[256];
    for (int i = threadIdx.x; i < DDIM; i += 256) os[i] = oattn[b * DDIM + i];
    __syncthreads();
    int t = threadIdx.x;
    int col = c0 + (t & 127);
    int d0 = (t >> 7) * 512;
    float acc = 0.f;
#pragma unroll 8
    for (int d = d0; d < d0 + 512; ++d)
        acc = fmaf(os[d], Wo[(size_t)d * DDIM + col], acc);
    ps[t] = acc;
    __syncthreads();
    if (t < 128)
        x[b * DDIM + col] = query[b * DDIM + col] + ps[t] + ps[t + 128] + bo[col];
}

// K6: out = LayerNorm(x) * gamma + beta; grid B
__global__ __launch_bounds__(256) void k_ln(const float* __restrict__ x,
                                            const float* __restrict__ gamma,
                                            const float* __restrict__ beta,
                                            float* __restrict__ out) {
    int b = blockIdx.x;
    int t = threadIdx.x;
    __shared__ float red[8];
    float xv[4];
    float lsum = 0.f;
#pragma unroll
    for (int k = 0; k < 4; ++k) {
        xv[k] = x[b * DDIM + t + k * 256];
        lsum += xv[k];
    }
#pragma unroll
    for (int off = 32; off > 0; off >>= 1) lsum += __shfl_xor(lsum, off, 64);
    if ((t & 63) == 0) red[t >> 6] = lsum;
    __syncthreads();
    float mu = (red[0] + red[1] + red[2] + red[3]) * (1.f / DDIM);
    float lsq = 0.f;
#pragma unroll
    for (int k = 0; k < 4; ++k) {
        float dx = xv[k] - mu;
        lsq += dx * dx;
    }
#pragma unroll
    for (int off = 32; off > 0; off >>= 1) lsq += __shfl_xor(lsq, off, 64);
    if ((t & 63) == 0) red[4 + (t >> 6)] = lsq;
    __syncthreads();
    float var = (red[4] + red[5] + red[6] + red[7]) * (1.f / DDIM);
    float rstd = rsqrtf(var + LNEPS);
#pragma unroll
    for (int k = 0; k < 4; ++k) {
        int c = t + k * 256;
        out[b * DDIM + c] = (xv[k] - mu) * rstd * gamma[c] + beta[c];
    }
}

extern "C" void kernel_launch(void* const* d_in, const int* in_sizes, int n_in,
                              void* d_out, int out_size, void* d_ws, size_t ws_size,
                              hipStream_t stream) {
    const float* query = (const float*)d_in[0];
    const float* ctx   = (const float*)d_in[1];
    const float* dist  = (const float*)d_in[2];
    const int*   mask  = (const int*)d_in[3];
    const float* Wq = (const float*)d_in[4];
    const float* bq = (const float*)d_in[5];
    const float* Wk = (const float*)d_in[6];
    const float* bk = (const float*)d_in[7];
    const float* Wv = (const float*)d_in[8];
    const float* bv = (const float*)d_in[9];
    const float* Wo = (const float*)d_in[10];
    const float* bo = (const float*)d_in[11];
    const float* gamma = (const float*)d_in[12];
    const float* beta  = (const float*)d_in[13];
    float* out = (float*)d_out;

    int B = in_sizes[0] / DDIM;        // 32
    int N = in_sizes[1] / (B * DDIM);  // 4096

    float* ws = (float*)d_ws;
    float* q = ws;                                                      // B*D
    unsigned short* qpb = (unsigned short*)(q + (size_t)B * DDIM);      // B*NH*D bf16
    float* sb = (float*)(qpb + (size_t)B * NH * DDIM);                  // B*NH
    unsigned short* partAb = (unsigned short*)(sb + (size_t)B * NH);    // B*NS*NH*D bf16
    float* partM = (float*)(partAb + (size_t)B * NS * NH * DDIM);       // B*NS*NH
    float* partL = partM + (size_t)B * NS * NH;                         // B*NS*NH
    float* oattn = partL + (size_t)B * NS * NH;                         // B*D
    float* xbuf = oattn + (size_t)B * DDIM;                             // B*D

    k_q<<<dim3(B, 8), 512, 0, stream>>>(query, Wq, bq, q);
    k_qp<<<dim3(DDIM / 16, B / 8), 256, 0, stream>>>(q, Wk, bk, qpb, sb);
    k_flash3<<<dim3(B, NS), 512, 0, stream>>>(ctx, qpb, sb, dist, mask,
                                              partAb, partM, partL, N);
    k_combv2<<<dim3(B, 8), 256, 0, stream>>>(partAb, partM, partL, Wv, bv, oattn);
    k_oproj<<<dim3(B, 8), 256, 0, stream>>>(query, oattn, Wo, bo, xbuf);
    k_ln<<<B, 256, 0, stream>>>(xbuf, gamma, beta, out);
}

// Round 19
// 215.752 us; speedup vs baseline: 1.0946x; 1.0946x over previous
//
#include <hip/hip_runtime.h>
#include <hip/hip_bf16.h>
#include <math.h>

#define DDIM 1024
#define NH 16
#define HDIM 64
#define SCALE 0.125f
#define DLAM -0.1f
#define LNEPS 1e-5f
#define NS 16      // n-splits (blocks per batch) for k_flash2
#define CHW 16     // chunk height (rows per chunk)
#define BROW 256   // rows per block = N/NS
#define CBSTR 1032 // padded LDS row stride (bf16 elems)

typedef short bf16x8 __attribute__((ext_vector_type(8)));
typedef float f32x4 __attribute__((ext_vector_type(4)));

__device__ inline unsigned short f2bf(float x) {
    return __builtin_bit_cast(unsigned short, __float2bfloat16(x));
}
__device__ inline float bf2f(unsigned short u) {
    return __builtin_bit_cast(float, (unsigned)u << 16);
}

// LDS-only barrier: waits DS ops (lgkmcnt) but leaves global loads in flight.
__device__ inline void wg_barrier_lds() {
    asm volatile("s_waitcnt lgkmcnt(0)" ::: "memory");
    __builtin_amdgcn_s_barrier();
    __builtin_amdgcn_sched_barrier(0);
}

// K1: q[b,c] = query[b,:] @ Wq[:,c] + bq[c]; grid (B,8) = 256 blocks
__global__ __launch_bounds__(512) void k_q(const float* __restrict__ query,
                                           const float* __restrict__ Wq,
                                           const float* __restrict__ bq,
                                           float* __restrict__ qout) {
    int b = blockIdx.x, c0 = blockIdx.y * 128;
    __shared__ float qs[DDIM];
    __shared__ float ps[512];
    int t = threadIdx.x;
    for (int i = t; i < DDIM; i += 512) qs[i] = query[b * DDIM + i];
    __syncthreads();
    int cl = t & 127;
    int col = c0 + cl;
    int d0 = (t >> 7) * 256;
    float acc = 0.f;
#pragma unroll 8
    for (int d = d0; d < d0 + 256; ++d)
        acc = fmaf(qs[d], Wq[(size_t)d * DDIM + col], acc);
    ps[t] = acc;
    __syncthreads();
    if (t < 128)
        qout[b * DDIM + col] = ps[t] + ps[t + 128] + ps[t + 256] + ps[t + 384] + bq[col];
}

// K2: qpb[(bg*8+bb),h,d] = bf16( SCALE * sum_j Wk[d, h*64+j] * q[bb, h*64+j] )
// sb[b,h] folded into the dt==0 blocks (qs already staged).
__global__ __launch_bounds__(256) void k_qp(const float* __restrict__ qin,
                                            const float* __restrict__ Wk,
                                            const float* __restrict__ bk,
                                            unsigned short* __restrict__ qpb,
                                            float* __restrict__ sb) {
    int dt = blockIdx.x, bg = blockIdx.y;
    __shared__ float qs[8][DDIM];  // 32 KB
    for (int i = threadIdx.x; i < 8 * DDIM; i += 256)
        qs[i >> 10][i & 1023] =
            qin[(size_t)(bg * 8 + (i >> 10)) * DDIM + (i & 1023)];
    __syncthreads();
    if (dt == 0 && threadIdx.x < 128) {
        int bb = threadIdx.x >> 4, h = threadIdx.x & 15;
        float a = 0.f;
#pragma unroll
        for (int j = 0; j < HDIM; ++j)
            a = fmaf(bk[h * HDIM + j], qs[bb][h * HDIM + j], a);
        sb[(bg * 8 + bb) * NH + h] = a * SCALE;
    }
    int h = threadIdx.x & 15, dl = threadIdx.x >> 4;
    int d = dt * 16 + dl;
    const float* wr = Wk + (size_t)d * DDIM + h * HDIM;
    float acc[8] = {0.f, 0.f, 0.f, 0.f, 0.f, 0.f, 0.f, 0.f};
#pragma unroll
    for (int j = 0; j < HDIM; ++j) {
        float wv = wr[j];
#pragma unroll
        for (int bb = 0; bb < 8; ++bb)
            acc[bb] = fmaf(wv, qs[bb][h * HDIM + j], acc[bb]);
    }
#pragma unroll
    for (int bb = 0; bb < 8; ++bb)
        qpb[((size_t)((bg * 8 + bb) * NH + h)) * DDIM + d] = f2bf(acc[bb] * SCALE);
}

// K3 (fused flash): R16 structure with bf16 partials. 256 thr = 4 waves,
// double-buffered cbuf, quad-interleaved stage-early, LDS-only barriers,
// scores + PV both on MFMA.
__global__ __launch_bounds__(256, 2) void k_flash2(
    const float* __restrict__ ctx, const unsigned short* __restrict__ qpb,
    const float* __restrict__ sb, const float* __restrict__ dist,
    const int* __restrict__ mask, unsigned short* __restrict__ partAb,
    float* __restrict__ partM, float* __restrict__ partL, int N) {
    __shared__ unsigned short cbuf[2][CHW][CBSTR];  // 66048 B
    __shared__ float red[4][CHW][17];               // 4352 B
    __shared__ float dls[BROW];

    int b = blockIdx.x, ns = blockIdx.y;
    int t = threadIdx.x, lane = t & 63, w = t >> 6;
    int m = lane & 15, g = lane >> 4;
    int nb0 = ns * BROW;
    const int NIT = BROW / CHW;  // 16

    {
        float dv = dist[(size_t)b * N + nb0 + t] * DLAM;
        dls[t] = mask[(size_t)b * N + nb0 + t] ? dv : -1e30f;
    }
    bf16x8 qf[8];
#pragma unroll
    for (int j = 0; j < 8; ++j)
        qf[j] = *reinterpret_cast<const bf16x8*>(
            qpb + ((size_t)(b * NH + m)) * DDIM + w * 256 + j * 32 + g * 8);
    float sbv = sb[b * NH + m];

    // acc[td][r] = out[h = g*4+r][d = w*256 + td*16 + (lane&15)]
    f32x4 acc[16];
#pragma unroll
    for (int td = 0; td < 16; ++td) acc[td] = (f32x4){0.f, 0.f, 0.f, 0.f};
    float m_run = -1e30f, l_run = 0.f;

    const float4* cb4 = reinterpret_cast<const float4*>(ctx) +
                        ((size_t)b * N + nb0) * (DDIM / 4);
    float4 inflight[16];

#define LOADC(c)                                                  \
    {                                                             \
        const float4* src = cb4 + (size_t)(c) * CHW * (DDIM / 4); \
        _Pragma("unroll") for (int i = 0; i < 16; ++i)            \
            inflight[i] = src[i * 256 + t];                       \
    }
#define LOAD4(qq, c)                                                  \
    {                                                                 \
        const float4* src = cb4 + (size_t)(c) * CHW * (DDIM / 4);     \
        _Pragma("unroll") for (int i = (qq) * 4; i < (qq) * 4 + 4; ++i) \
            inflight[i] = src[i * 256 + t];                           \
    }
#define WRITECB(buf)                                                         \
    {                                                                        \
        _Pragma("unroll") for (int i = 0; i < 16; ++i) {                     \
            float4 v = inflight[i];                                          \
            unsigned lo = (unsigned)f2bf(v.x) | ((unsigned)f2bf(v.y) << 16); \
            unsigned hi = (unsigned)f2bf(v.z) | ((unsigned)f2bf(v.w) << 16); \
            *reinterpret_cast<uint2*>(&cbuf[buf][i][t * 4]) =                \
                make_uint2(lo, hi);                                          \
        }                                                                    \
    }
#define WRITE4(qq, buf)                                                      \
    {                                                                        \
        _Pragma("unroll") for (int i = (qq) * 4; i < (qq) * 4 + 4; ++i) {    \
            float4 v = inflight[i];                                          \
            unsigned lo = (unsigned)f2bf(v.x) | ((unsigned)f2bf(v.y) << 16); \
            unsigned hi = (unsigned)f2bf(v.z) | ((unsigned)f2bf(v.w) << 16); \
            *reinterpret_cast<uint2*>(&cbuf[buf][i][t * 4]) =                \
                make_uint2(lo, hi);                                          \
        }                                                                    \
    }

    LOADC(0);
    WRITECB(0);
    LOADC(1);

    int dcol = lane & 15;
    for (int c = 0; c < NIT; ++c) {
        wg_barrier_lds();  // A: cbuf[buf] ready; prev PV complete
        int buf = c & 1;
        if (c + 2 < NIT) {
#pragma unroll
            for (int q = 0; q < 4; ++q) {
                WRITE4(q, buf ^ 1);
                __builtin_amdgcn_sched_barrier(0);
                LOAD4(q, c + 2);
                __builtin_amdgcn_sched_barrier(0);
            }
        } else if (c + 1 < NIT) {
            WRITECB(buf ^ 1);
        }
        // ---- scores (wave K-slice 256) ----
        f32x4 cS = {0.f, 0.f, 0.f, 0.f};
#pragma unroll
        for (int j = 0; j < 8; ++j) {
            bf16x8 a = *reinterpret_cast<const bf16x8*>(
                &cbuf[buf][m][w * 256 + j * 32 + g * 8]);
            cS = __builtin_amdgcn_mfma_f32_16x16x32_bf16(a, qf[j], cS, 0, 0, 0);
        }
#pragma unroll
        for (int r = 0; r < 4; ++r) red[w][g * 4 + r][m] = cS[r];
        wg_barrier_lds();  // B: red ready
        float S[4];
#pragma unroll
        for (int r = 0; r < 4; ++r) {
            int n = g * 4 + r;
            S[r] = red[0][n][m] + red[1][n][m] + red[2][n][m] + red[3][n][m] +
                   sbv + dls[c * CHW + n];
        }
        float cm = fmaxf(fmaxf(S[0], S[1]), fmaxf(S[2], S[3]));
        cm = fmaxf(cm, __shfl_xor(cm, 16, 64));
        cm = fmaxf(cm, __shfl_xor(cm, 32, 64));
        float mnew = fmaxf(m_run, cm);
        float f = __expf(m_run - mnew);
        float p[4];
        float ls = 0.f;
#pragma unroll
        for (int r = 0; r < 4; ++r) {
            p[r] = __expf(S[r] - mnew);
            ls += p[r];
        }
        ls += __shfl_xor(ls, 16, 64);
        ls += __shfl_xor(ls, 32, 64);
        l_run = l_run * f + ls;
        m_run = mnew;
        // ---- A-frag from p (thread (m,g) supplies A[m][k=g*8+j]=P[g*4+j][m]) ----
        bf16x8 pa = (bf16x8){0, 0, 0, 0, 0, 0, 0, 0};
        pa[0] = (short)f2bf(p[0]);
        pa[1] = (short)f2bf(p[1]);
        pa[2] = (short)f2bf(p[2]);
        pa[3] = (short)f2bf(p[3]);
        // per-head rescale factors for heads g*4+r
        float fr[4];
#pragma unroll
        for (int r = 0; r < 4; ++r) fr[r] = __shfl(f, (lane >> 4) * 4 + r, 64);
#pragma unroll
        for (int td = 0; td < 16; ++td) {
            acc[td][0] *= fr[0];
            acc[td][1] *= fr[1];
            acc[td][2] *= fr[2];
            acc[td][3] *= fr[3];
        }
        // ---- PV via MFMA: B[k=g*8+j][dcol] = cbuf[g*4+j][d], j<4; zero j>=4 ----
#pragma unroll
        for (int td = 0; td < 16; ++td) {
            int dc = w * 256 + td * 16 + dcol;
            bf16x8 bb = (bf16x8){0, 0, 0, 0, 0, 0, 0, 0};
            bb[0] = (short)cbuf[buf][g * 4 + 0][dc];
            bb[1] = (short)cbuf[buf][g * 4 + 1][dc];
            bb[2] = (short)cbuf[buf][g * 4 + 2][dc];
            bb[3] = (short)cbuf[buf][g * 4 + 3][dc];
            acc[td] = __builtin_amdgcn_mfma_f32_16x16x32_bf16(pa, bb, acc[td], 0, 0, 0);
        }
        // loop barrier A doubles as "PV done with cbuf[buf]"
    }

    // epilogue: bf16 partials (thread holds h=g*4+r, d=w*256+td*16+dcol)
#pragma unroll
    for (int td = 0; td < 16; ++td) {
#pragma unroll
        for (int r = 0; r < 4; ++r) {
            int h = g * 4 + r;
            partAb[((size_t)((b * NS + ns) * NH + h)) * DDIM + w * 256 + td * 16 +
                   dcol] = f2bf(acc[td][r]);
        }
    }
    if (t < NH) {
        partM[(b * NS + ns) * NH + t] = m_run;
        partL[(b * NS + ns) * NH + t] = l_run;
    }
#undef LOADC
#undef LOAD4
#undef WRITECB
#undef WRITE4
}

// K4 (fused comb + vproj): grid (B, 8), 256 blocks. Comb 2 heads from bf16
// partA into LDS, then the k_vproj GEMV. ctxa round-trip eliminated.
__global__ __launch_bounds__(256) void k_combv2(const unsigned short* __restrict__ partAb,
                                                const float* __restrict__ partM,
                                                const float* __restrict__ partL,
                                                const float* __restrict__ Wv,
                                                const float* __restrict__ bv,
                                                float* __restrict__ oattn) {
    int b = blockIdx.x, c0 = blockIdx.y * 128;
    int h0 = c0 >> 6;
    __shared__ float cs[2][DDIM];   // 8 KB
    __shared__ float wn_s[2][NS];   // 128 B
    __shared__ float ps[256];       // 1 KB
    int t = threadIdx.x;
    if (t < 2) {
        int h = h0 + t;
        float M = -1e30f;
#pragma unroll
        for (int ns = 0; ns < NS; ++ns)
            M = fmaxf(M, partM[(b * NS + ns) * NH + h]);
        float den = 0.f;
#pragma unroll
        for (int ns = 0; ns < NS; ++ns)
            den = fmaf(__expf(partM[(b * NS + ns) * NH + h] - M),
                       partL[(b * NS + ns) * NH + h], den);
        float inv = 1.f / den;
#pragma unroll
        for (int ns = 0; ns < NS; ++ns)
            wn_s[t][ns] = __expf(partM[(b * NS + ns) * NH + h] - M) * inv;
    }
    __syncthreads();
    for (int i = t; i < 2 * DDIM; i += 256) {
        int hh = i >> 10, d = i & 1023;
        float s = 0.f;
#pragma unroll
        for (int ns = 0; ns < NS; ++ns)
            s = fmaf(wn_s[hh][ns],
                     bf2f(partAb[((size_t)((b * NS + ns) * NH + h0 + hh)) * DDIM + d]),
                     s);
        cs[hh][d] = s;
    }
    __syncthreads();
    int cl = t & 127;
    int col = c0 + cl;
    int hl = cl >> 6;
    int d0 = (t >> 7) * 512;
    float acc = 0.f;
#pragma unroll 8
    for (int d = d0; d < d0 + 512; ++d)
        acc = fmaf(cs[hl][d], Wv[(size_t)d * DDIM + col], acc);
    ps[t] = acc;
    __syncthreads();
    if (t < 128) oattn[b * DDIM + col] = ps[t] + ps[t + 128] + bv[col];
}

// K5: x[b,c] = query[b,c] + oattn[b,:] . Wo[:,c] + bo[c]; grid (B, 8)
__global__ __launch_bounds__(256) void k_oproj(const float* __restrict__ query,
                                               const float* __restrict__ oattn,
                                               const float* __restrict__ Wo,
                                               const float* __restrict__ bo,
                                               float* __restrict__ x) {
    int b = blockIdx.x, c0 = blockIdx.y * 128;
    __shared__ float os[DDIM];
    __shared__ float ps[256];
    for (int i = threadIdx.x; i < DDIM; i += 256) os[i] = oattn[b * DDIM + i];
    __syncthreads();
    int t = threadIdx.x;
    int col = c0 + (t & 127);
    int d0 = (t >> 7) * 512;
    float acc = 0.f;
#pragma unroll 8
    for (int d = d0; d < d0 + 512; ++d)
        acc = fmaf(os[d], Wo[(size_t)d * DDIM + col], acc);
    ps[t] = acc;
    __syncthreads();
    if (t < 128)
        x[b * DDIM + col] = query[b * DDIM + col] + ps[t] + ps[t + 128] + bo[col];
}

// K6: out = LayerNorm(x) * gamma + beta; grid B
__global__ __launch_bounds__(256) void k_ln(const float* __restrict__ x,
                                            const float* __restrict__ gamma,
                                            const float* __restrict__ beta,
                                            float* __restrict__ out) {
    int b = blockIdx.x;
    int t = threadIdx.x;
    __shared__ float red[8];
    float xv[4];
    float lsum = 0.f;
#pragma unroll
    for (int k = 0; k < 4; ++k) {
        xv[k] = x[b * DDIM + t + k * 256];
        lsum += xv[k];
    }
#pragma unroll
    for (int off = 32; off > 0; off >>= 1) lsum += __shfl_xor(lsum, off, 64);
    if ((t & 63) == 0) red[t >> 6] = lsum;
    __syncthreads();
    float mu = (red[0] + red[1] + red[2] + red[3]) * (1.f / DDIM);
    float lsq = 0.f;
#pragma unroll
    for (int k = 0; k < 4; ++k) {
        float dx = xv[k] - mu;
        lsq += dx * dx;
    }
#pragma unroll
    for (int off = 32; off > 0; off >>= 1) lsq += __shfl_xor(lsq, off, 64);
    if ((t & 63) == 0) red[4 + (t >> 6)] = lsq;
    __syncthreads();
    float var = (red[4] + red[5] + red[6] + red[7]) * (1.f / DDIM);
    float rstd = rsqrtf(var + LNEPS);
#pragma unroll
    for (int k = 0; k < 4; ++k) {
        int c = t + k * 256;
        out[b * DDIM + c] = (xv[k] - mu) * rstd * gamma[c] + beta[c];
    }
}

extern "C" void kernel_launch(void* const* d_in, const int* in_sizes, int n_in,
                              void* d_out, int out_size, void* d_ws, size_t ws_size,
                              hipStream_t stream) {
    const float* query = (const float*)d_in[0];
    const float* ctx   = (const float*)d_in[1];
    const float* dist  = (const float*)d_in[2];
    const int*   mask  = (const int*)d_in[3];
    const float* Wq = (const float*)d_in[4];
    const float* bq = (const float*)d_in[5];
    const float* Wk = (const float*)d_in[6];
    const float* bk = (const float*)d_in[7];
    const float* Wv = (const float*)d_in[8];
    const float* bv = (const float*)d_in[9];
    const float* Wo = (const float*)d_in[10];
    const float* bo = (const float*)d_in[11];
    const float* gamma = (const float*)d_in[12];
    const float* beta  = (const float*)d_in[13];
    float* out = (float*)d_out;

    int B = in_sizes[0] / DDIM;        // 32
    int N = in_sizes[1] / (B * DDIM);  // 4096

    float* ws = (float*)d_ws;
    float* q = ws;                                                      // B*D
    unsigned short* qpb = (unsigned short*)(q + (size_t)B * DDIM);      // B*NH*D bf16
    float* sb = (float*)(qpb + (size_t)B * NH * DDIM);                  // B*NH
    unsigned short* partAb = (unsigned short*)(sb + (size_t)B * NH);    // B*NS*NH*D bf16
    float* partM = (float*)(partAb + (size_t)B * NS * NH * DDIM);       // B*NS*NH
    float* partL = partM + (size_t)B * NS * NH;                         // B*NS*NH
    float* oattn = partL + (size_t)B * NS * NH;                         // B*D
    float* xbuf = oattn + (size_t)B * DDIM;                             // B*D

    k_q<<<dim3(B, 8), 512, 0, stream>>>(query, Wq, bq, q);
    k_qp<<<dim3(DDIM / 16, B / 8), 256, 0, stream>>>(q, Wk, bk, qpb, sb);
    k_flash2<<<dim3(B, NS), 256, 0, stream>>>(ctx, qpb, sb, dist, mask,
                                              partAb, partM, partL, N);
    k_combv2<<<dim3(B, 8), 256, 0, stream>>>(partAb, partM, partL, Wv, bv, oattn);
    k_oproj<<<dim3(B, 8), 256, 0, stream>>>(query, oattn, Wo, bo, xbuf);
    k_ln<<<B, 256, 0, stream>>>(xbuf, gamma, beta, out);
}